// Round 1
// baseline (10999.338 us; speedup 1.0000x reference)
//
#include <hip/hip_runtime.h>
#include <math.h>

// Problem constants
#define B_    32
#define T_    1000
#define E_    512
#define D_    1024
#define A_    512
#define C_    10
#define F_    100
#define ODIM_ 5000
#define OLEN_ 101
#define SOS_  4998

// ---- workspace layout (float offsets) ----
#define OFF_PRE   0u
#define N_PRE     (32u*1000u*512u)          // 16,384,000
#define OFF_DEC   (OFF_PRE + N_PRE)         // [B][A]
#define N_DEC     (32u*512u)
#define OFF_CONV  (OFF_DEC + N_DEC)         // [B][C][T]
#define N_CONVB   (32u*10u*1000u)
#define OFF_EB    (OFF_CONV + N_CONVB)      // [B][T] stores s_t = 2*e_t
#define N_EB      (32u*1000u)
#define OFF_AW    (OFF_EB + N_EB)           // [B][T] attention weights
#define OFF_MS    (OFF_AW + N_EB)           // [B][100] chunk max of s_t
#define N_MS      (32u*100u)
#define OFF_SS    (OFF_MS + N_MS)           // [B][100] chunk sum exp(s_t - m)
#define OFF_CTX   (OFF_SS + N_MS)           // [B][E]
#define N_CTX     (32u*512u)
#define OFF_GP    (OFF_CTX + N_CTX)         // 8 slots x [B][4096] ey/z gate partials
#define N_GP      (8u*32u*4096u)
#define OFF_Z     (OFF_GP + N_GP)           // [B][D]
#define N_Z       (32u*1024u)
#define OFF_C     (OFF_Z + N_Z)             // [B][D]
#define OFF_ZALL  (OFF_C + N_Z)             // [101][B][D]

// ---- fast transcendentals ----
__device__ __forceinline__ float fast_tanh(float x) {
    float cx = fminf(8.f, fmaxf(-8.f, x));
    float e = __expf(2.f * cx);
    return (e - 1.f) * __builtin_amdgcn_rcpf(e + 1.f);
}
__device__ __forceinline__ float fast_sigmoid(float x) {
    float cx = fminf(30.f, fmaxf(-30.f, x));
    return __builtin_amdgcn_rcpf(1.f + __expf(-cx));
}

// ---------------- init: z=0, c=0, ctx=0, aw=1/T ----------------
__global__ __launch_bounds__(256) void k_init(float* ws) {
    int i = blockIdx.x * 256 + threadIdx.x;
    if (i < (int)N_Z) { ws[OFF_Z + i] = 0.f; ws[OFF_C + i] = 0.f; }
    if (i < (int)N_CTX) ws[OFF_CTX + i] = 0.f;
    if (i < (int)N_EB) ws[OFF_AW + i] = 1.0f / (float)T_;
}

// ---------------- pre = hpad @ w_enc^T + b_enc (once) ----------------
__global__ __launch_bounds__(256) void k_pre(const float* __restrict__ hp,
                                             const float* __restrict__ we,
                                             const float* __restrict__ be,
                                             float* __restrict__ pre) {
    __shared__ float As[64][68];
    __shared__ float Bs[64][68];
    int m0 = blockIdx.y * 64, n0 = blockIdx.x * 64;
    int tid = threadIdx.x;
    int tr = tid >> 4, tc = tid & 15;
    float acc[4][4] = {};
    for (int k0 = 0; k0 < 512; k0 += 64) {
        for (int i = tid; i < 1024; i += 256) {
            int m = i >> 4, kq = (i & 15) << 2;
            float4 v = *(const float4*)&hp[(size_t)(m0 + m) * 512 + k0 + kq];
            As[kq + 0][m] = v.x; As[kq + 1][m] = v.y; As[kq + 2][m] = v.z; As[kq + 3][m] = v.w;
            float4 w = *(const float4*)&we[(size_t)(n0 + m) * 512 + k0 + kq];
            Bs[kq + 0][m] = w.x; Bs[kq + 1][m] = w.y; Bs[kq + 2][m] = w.z; Bs[kq + 3][m] = w.w;
        }
        __syncthreads();
        #pragma unroll 16
        for (int kk = 0; kk < 64; ++kk) {
            float4 av = *(const float4*)&As[kk][tr << 2];
            float4 bv = *(const float4*)&Bs[kk][tc << 2];
            float a[4] = {av.x, av.y, av.z, av.w};
            float b[4] = {bv.x, bv.y, bv.z, bv.w};
            #pragma unroll
            for (int i = 0; i < 4; i++)
                #pragma unroll
                for (int j = 0; j < 4; j++) acc[i][j] += a[i] * b[j];
        }
        __syncthreads();
    }
    #pragma unroll
    for (int i = 0; i < 4; i++) {
        int m = m0 + (tr << 2) + i;
        int n = n0 + (tc << 2);
        float4 o;
        o.x = acc[i][0] + be[n + 0];
        o.y = acc[i][1] + be[n + 1];
        o.z = acc[i][2] + be[n + 2];
        o.w = acc[i][3] + be[n + 3];
        *(float4*)&pre[(size_t)m * 512 + n] = o;
    }
}

// ---------------- phase 1: dec + conv + ey/z gate partials + ctx zero ----------------
// blocks [0,1024): dec (wave per (a, 4 b's); 4096 waves -> FULL b coverage, fixes prior bug)
// blocks [1024,1344): conv (b = blk/10, c = blk%10)
// blocks [1344,1600): gates ey/z (32 ntiles of 128 x 8 ksplits of 256; slots 0..7)
__global__ __launch_bounds__(256) void k_prepA(const float* __restrict__ wdec,
                                               const float* __restrict__ wconv,
                                               const float* __restrict__ wih,
                                               const float* __restrict__ whh,
                                               const float* __restrict__ embed,
                                               const int* __restrict__ ys,
                                               float* ws, int step) {
    int tid = threadIdx.x;
    if (blockIdx.x < 1024) {
        if (blockIdx.x < 64) ws[OFF_CTX + blockIdx.x * 256 + tid] = 0.f;   // zero ctx for this step
        int w = blockIdx.x * 4 + (tid >> 6);      // 0..4095
        int lane = tid & 63;
        int a = w >> 3, bg = w & 7;               // 512 a x 8 groups of 4 b
        const float4* wr = (const float4*)(wdec + (size_t)a * 1024);
        float4 w4[4];
        #pragma unroll
        for (int i = 0; i < 4; i++) w4[i] = wr[i * 64 + lane];
        float acc0 = 0.f, acc1 = 0.f, acc2 = 0.f, acc3 = 0.f;
        {
            const float4* zr = (const float4*)(ws + OFF_Z + (bg * 4 + 0) * 1024);
            #pragma unroll
            for (int i = 0; i < 4; i++) { float4 z4 = zr[i * 64 + lane];
                acc0 += w4[i].x*z4.x + w4[i].y*z4.y + w4[i].z*z4.z + w4[i].w*z4.w; }
        }
        {
            const float4* zr = (const float4*)(ws + OFF_Z + (bg * 4 + 1) * 1024);
            #pragma unroll
            for (int i = 0; i < 4; i++) { float4 z4 = zr[i * 64 + lane];
                acc1 += w4[i].x*z4.x + w4[i].y*z4.y + w4[i].z*z4.z + w4[i].w*z4.w; }
        }
        {
            const float4* zr = (const float4*)(ws + OFF_Z + (bg * 4 + 2) * 1024);
            #pragma unroll
            for (int i = 0; i < 4; i++) { float4 z4 = zr[i * 64 + lane];
                acc2 += w4[i].x*z4.x + w4[i].y*z4.y + w4[i].z*z4.z + w4[i].w*z4.w; }
        }
        {
            const float4* zr = (const float4*)(ws + OFF_Z + (bg * 4 + 3) * 1024);
            #pragma unroll
            for (int i = 0; i < 4; i++) { float4 z4 = zr[i * 64 + lane];
                acc3 += w4[i].x*z4.x + w4[i].y*z4.y + w4[i].z*z4.z + w4[i].w*z4.w; }
        }
        #pragma unroll
        for (int off = 32; off > 0; off >>= 1) {
            acc0 += __shfl_xor(acc0, off, 64);
            acc1 += __shfl_xor(acc1, off, 64);
            acc2 += __shfl_xor(acc2, off, 64);
            acc3 += __shfl_xor(acc3, off, 64);
        }
        if (lane == 0) {
            ws[OFF_DEC + (bg * 4 + 0) * 512 + a] = acc0;
            ws[OFF_DEC + (bg * 4 + 1) * 512 + a] = acc1;
            ws[OFF_DEC + (bg * 4 + 2) * 512 + a] = acc2;
            ws[OFF_DEC + (bg * 4 + 3) * 512 + a] = acc3;
        }
    } else if (blockIdx.x < 1344) {
        int blk = blockIdx.x - 1024;   // 0..319
        int b = blk / 10, c = blk - b * 10;
        if (tid >= 250) return;
        int t = tid * 4;
        const float* ar = ws + OFF_AW + b * 1000;
        const float* wc = wconv + c * 201;
        float a0, a1, a2, a3;
        a0 = (t - 100 >= 0) ? ar[t - 100] : 0.f;
        a1 = (t -  99 >= 0) ? ar[t -  99] : 0.f;
        a2 = (t -  98 >= 0) ? ar[t -  98] : 0.f;
        a3 = (t -  97 >= 0) ? ar[t -  97] : 0.f;
        float c0 = 0.f, c1 = 0.f, c2 = 0.f, c3 = 0.f;
        #pragma unroll 4
        for (int j = 0; j < 201; ++j) {
            float w = wc[j];
            c0 += a0 * w; c1 += a1 * w; c2 += a2 * w; c3 += a3 * w;
            a0 = a1; a1 = a2; a2 = a3;
            int ni = t + j - 96;
            a3 = (ni >= 0 && ni < 1000) ? ar[ni] : 0.f;
        }
        float* o = ws + OFF_CONV + (size_t)(b * 10 + c) * 1000 + t;
        o[0] = c0; o[1] = c1; o[2] = c2; o[3] = c3;
    } else {
        // ey/z gate partials: C[b][n] partial over K-range; slots 0..3 = ey (w_ih cols 0..1024),
        // slots 4..7 = z (w_hh). ctx cols (1024..1536 of w_ih) handled in k_gl.
        __shared__ float wlds[32][132];
        __shared__ float xs[32][36];
        int blk = blockIdx.x - 1344;       // 0..255
        int nt = blk & 31, ks = blk >> 5;  // 32 ntiles x 8 ksplits
        int n0 = nt * 128;
        bool isE = (ks < 4);
        int kloc = isE ? ks * 256 : (ks - 4) * 256;  // col offset within w_ih-ey / w_hh
        int r = tid >> 1, h = tid & 1;     // w staging: 128 rows, 16 k each
        int bx = tid >> 3, q8 = tid & 7;   // x staging: 32 b, 4 k each
        int tok = (step == 0) ? SOS_ : ys[bx * 100 + step - 1];
        const float* xsrc = isE ? (embed + (size_t)tok * 1024 + kloc)
                                : (ws + OFF_Z + (size_t)bx * 1024 + kloc);
        int nq = tid & 31, bq = tid >> 5;  // compute: 32 ngroups x 8 bgroups
        float acc[4][4] = {};
        for (int kc = 0; kc < 8; ++kc) {
            int koff = kc * 32;
            {
                const float* wrow = isE ? (wih + (size_t)(n0 + r) * 1536 + kloc + koff + h * 16)
                                        : (whh + (size_t)(n0 + r) * 1024 + kloc + koff + h * 16);
                #pragma unroll
                for (int j = 0; j < 4; ++j) {
                    float4 v = *(const float4*)&wrow[j * 4];
                    int kb = h * 16 + j * 4;
                    wlds[kb + 0][r] = v.x; wlds[kb + 1][r] = v.y;
                    wlds[kb + 2][r] = v.z; wlds[kb + 3][r] = v.w;
                }
            }
            {
                float4 v = *(const float4*)&xsrc[koff + q8 * 4];
                xs[q8 * 4 + 0][bx] = v.x; xs[q8 * 4 + 1][bx] = v.y;
                xs[q8 * 4 + 2][bx] = v.z; xs[q8 * 4 + 3][bx] = v.w;
            }
            __syncthreads();
            #pragma unroll 8
            for (int kk = 0; kk < 32; ++kk) {
                float4 wv = *(const float4*)&wlds[kk][nq * 4];
                float4 xv = *(const float4*)&xs[kk][bq * 4];
                float wa[4] = {wv.x, wv.y, wv.z, wv.w};
                float xa[4] = {xv.x, xv.y, xv.z, xv.w};
                #pragma unroll
                for (int i = 0; i < 4; i++)
                    #pragma unroll
                    for (int j = 0; j < 4; j++) acc[i][j] += wa[i] * xa[j];
            }
            __syncthreads();
        }
        float* gp = ws + OFF_GP + (size_t)(ks * 32 + bq * 4) * 4096 + n0 + nq * 4;
        #pragma unroll
        for (int j = 0; j < 4; j++)
            #pragma unroll
            for (int i = 0; i < 4; i++)
                gp[(size_t)j * 4096 + i] = acc[i][j];
    }
}

// ---------------- phase 2: energy + per-chunk softmax stats ----------------
// wave per (b, chunk of 10 t). 3200 waves = 800 blocks x 4 waves.
// EB stores s_t = 2*(e_t); stats: chunk max M and sum exp(s-M).
__global__ __launch_bounds__(256) void k_energy2(const float* __restrict__ watt,
                                                 const float* __restrict__ gvec,
                                                 const float* __restrict__ bg,
                                                 float* ws) {
    int w = blockIdx.x * 4 + (threadIdx.x >> 6);   // 0..3199
    int lane = threadIdx.x & 63;
    int b = w / 100;
    int ch = w - b * 100;
    int t0 = ch * 10;
    int a0 = lane * 4, a1 = 256 + lane * 4;
    float wr[8][10];
    #pragma unroll
    for (int i = 0; i < 4; i++)
        #pragma unroll
        for (int c = 0; c < 10; c++) {
            wr[i][c]     = watt[(a0 + i) * 10 + c];
            wr[4 + i][c] = watt[(a1 + i) * 10 + c];
        }
    float4 d0 = *(const float4*)&ws[OFF_DEC + b * 512 + a0];
    float4 d1 = *(const float4*)&ws[OFF_DEC + b * 512 + a1];
    float4 g0 = *(const float4*)&gvec[a0];
    float4 g1 = *(const float4*)&gvec[a1];
    float dc[8] = {d0.x, d0.y, d0.z, d0.w, d1.x, d1.y, d1.z, d1.w};
    float gv[8] = {g0.x, g0.y, g0.z, g0.w, g1.x, g1.y, g1.z, g1.w};
    float bgv = bg[0];
    const float* convb = ws + OFF_CONV + b * 10000;
    float M = -1e30f, S = 0.f;
    for (int it = 0; it < 10; ++it) {
        int t = t0 + it;
        const float* pr = ws + OFF_PRE + (size_t)(b * 1000 + t) * 512;
        float4 p0 = *(const float4*)&pr[a0];
        float4 p1 = *(const float4*)&pr[a1];
        float cv[10];
        #pragma unroll
        for (int c = 0; c < 10; c++) cv[c] = convb[c * 1000 + t];
        float pa[8] = {p0.x, p0.y, p0.z, p0.w, p1.x, p1.y, p1.z, p1.w};
        float acc = 0.f;
        #pragma unroll
        for (int i = 0; i < 8; i++) {
            float s = pa[i] + dc[i];
            #pragma unroll
            for (int c = 0; c < 10; c++) s += cv[c] * wr[i][c];
            acc += gv[i] * fast_tanh(s);
        }
        #pragma unroll
        for (int off = 32; off > 0; off >>= 1) acc += __shfl_xor(acc, off, 64);
        float st = 2.f * (acc + bgv);
        if (lane == 0) ws[OFF_EB + b * 1000 + t] = st;
        float Mn = fmaxf(M, st);
        S = S * __expf(M - Mn) + __expf(st - Mn);
        M = Mn;
    }
    if (lane == 0) {
        ws[OFF_MS + b * 100 + ch] = M;
        ws[OFF_SS + b * 100 + ch] = S;
    }
}

// ---------------- phase 3: softmax-normalize + aw write + ctx accumulate ----------------
// grid = 32 b x 32 tsplit; 128 threads (float4 over e)
__global__ __launch_bounds__(128) void k_ctx2(const float* __restrict__ hp, float* ws) {
    __shared__ float sm[100], ssum[100], wsh[32];
    int b = blockIdx.x >> 5, ts = blockIdx.x & 31;
    int tid = threadIdx.x;
    if (tid < 100) {
        sm[tid]   = ws[OFF_MS + b * 100 + tid];
        ssum[tid] = ws[OFF_SS + b * 100 + tid];
    }
    __syncthreads();
    float M = -1e30f;
    for (int i = 0; i < 100; i++) M = fmaxf(M, sm[i]);
    float S = 0.f;
    for (int i = 0; i < 100; i++) S += ssum[i] * __expf(sm[i] - M);
    float invS = __builtin_amdgcn_rcpf(S);
    int t0 = ts * 32;
    if (tid < 32) {
        int t = t0 + tid;
        float wv = 0.f;
        if (t < 1000) {
            wv = __expf(ws[OFF_EB + b * 1000 + t] - M) * invS;
            ws[OFF_AW + b * 1000 + t] = wv;
        }
        wsh[tid] = wv;
    }
    __syncthreads();
    int t1 = t0 + 32; if (t1 > 1000) t1 = 1000;
    const float4* hp4 = (const float4*)hp;
    float4 acc = make_float4(0.f, 0.f, 0.f, 0.f);
    for (int t = t0; t < t1; ++t) {
        float wv = wsh[t - t0];
        float4 h = hp4[(size_t)(b * 1000 + t) * 128 + tid];
        acc.x += wv * h.x; acc.y += wv * h.y; acc.z += wv * h.z; acc.w += wv * h.w;
    }
    float* cx = ws + OFF_CTX + b * 512 + tid * 4;
    atomicAdd(cx + 0, acc.x); atomicAdd(cx + 1, acc.y);
    atomicAdd(cx + 2, acc.z); atomicAdd(cx + 3, acc.w);
}

// ---------------- phase 4: ctx-gates (full K=512 per d-slice) + partial combine + LSTM ----------------
// 128 blocks x 128 thr. Block owns 8 d's -> 32 gate rows (q*1024 + d0 + dl), K = ctx 512.
__global__ __launch_bounds__(128) void k_gl(const float* __restrict__ wih,
                                            const float* __restrict__ bih,
                                            const float* __restrict__ bhh,
                                            float* ws, int step) {
    __shared__ float wlds[32][36];
    __shared__ float xs[32][36];
    __shared__ float gl[32][33];
    int tid = threadIdx.x;
    int d0 = blockIdx.x * 8;
    int r = tid >> 2, h = tid & 3;     // w staging: 32 rows, 8 k each
    int ng_r = (r >> 3) * 1024 + d0 + (r & 7);
    const float* wrow = wih + (size_t)ng_r * 1536 + 1024 + h * 8;
    int bx = tid >> 2, q4 = tid & 3;   // x staging: 32 b, 8 k each
    const float* xsrc = ws + OFF_CTX + (size_t)bx * 512 + q4 * 8;
    int nq = tid & 7, bq = tid >> 3;   // compute: 8 ngroups(4n) x 16 bgroups(2b)
    float acc[4][2] = {};
    for (int kc = 0; kc < 16; ++kc) {
        int k0 = kc * 32;
        {
            #pragma unroll
            for (int j = 0; j < 2; ++j) {
                float4 v = *(const float4*)&wrow[k0 + j * 4];
                int kb = h * 8 + j * 4;
                wlds[kb + 0][r] = v.x; wlds[kb + 1][r] = v.y;
                wlds[kb + 2][r] = v.z; wlds[kb + 3][r] = v.w;
            }
        }
        {
            #pragma unroll
            for (int j = 0; j < 2; ++j) {
                float4 v = *(const float4*)&xsrc[k0 + j * 4];
                int kb = q4 * 8 + j * 4;
                xs[kb + 0][bx] = v.x; xs[kb + 1][bx] = v.y;
                xs[kb + 2][bx] = v.z; xs[kb + 3][bx] = v.w;
            }
        }
        __syncthreads();
        #pragma unroll 8
        for (int kk = 0; kk < 32; ++kk) {
            float4 wv = *(const float4*)&wlds[kk][nq * 4];
            float x0 = xs[kk][bq * 2 + 0];
            float x1 = xs[kk][bq * 2 + 1];
            acc[0][0] += wv.x * x0; acc[0][1] += wv.x * x1;
            acc[1][0] += wv.y * x0; acc[1][1] += wv.y * x1;
            acc[2][0] += wv.z * x0; acc[2][1] += wv.z * x1;
            acc[3][0] += wv.w * x0; acc[3][1] += wv.w * x1;
        }
        __syncthreads();
    }
    // combine: + biases + 8 ey/z partial slots
    #pragma unroll
    for (int i = 0; i < 4; i++) {
        int nl = nq * 4 + i;                       // 0..31
        int ng = (nl >> 3) * 1024 + d0 + (nl & 7); // global gate row
        float bb = bih[ng] + bhh[ng];
        #pragma unroll
        for (int j = 0; j < 2; j++) {
            int b = bq * 2 + j;
            float s = acc[i][j] + bb;
            #pragma unroll
            for (int sl = 0; sl < 8; sl++)
                s += ws[OFF_GP + (size_t)(sl * 32 + b) * 4096 + ng];
            gl[nl][b] = s;
        }
    }
    __syncthreads();
    // LSTM elementwise: 8 d x 32 b = 256 outputs, 2 per thread
    #pragma unroll
    for (int u = 0; u < 2; u++) {
        int o = tid * 2 + u;
        int dl = o >> 5, b = o & 31;
        float gi = gl[dl][b];
        float gf = gl[8 + dl][b];
        float gg = gl[16 + dl][b];
        float go = gl[24 + dl][b];
        int id = b * 1024 + d0 + dl;
        float c_old = ws[OFF_C + id];
        float si = fast_sigmoid(gi);
        float sf = fast_sigmoid(gf);
        float so = fast_sigmoid(go);
        float cn = sf * c_old + si * fast_tanh(gg);
        float hh = so * fast_tanh(cn);
        ws[OFF_C + id] = cn;
        ws[OFF_Z + id] = hh;
        ws[OFF_ZALL + ((size_t)step * 32 + b) * 1024 + d0 + dl] = hh;
    }
}

// ---------------- final: out = zall @ w_out^T + b_out ----------------
__global__ __launch_bounds__(256) void k_out(const float* __restrict__ zall,
                                             const float* __restrict__ wo,
                                             const float* __restrict__ bo,
                                             float* __restrict__ out) {
    __shared__ float As[64][68];
    __shared__ float Bs[64][68];
    int m0 = blockIdx.y * 64, n0 = blockIdx.x * 64;
    int tid = threadIdx.x;
    int tr = tid >> 4, tc = tid & 15;
    float acc[4][4] = {};
    for (int k0 = 0; k0 < 1024; k0 += 64) {
        for (int i = tid; i < 1024; i += 256) {
            int m = i >> 4, kq = (i & 15) << 2;
            int gm = m0 + m;
            float4 v = (gm < 3232) ? *(const float4*)&zall[(size_t)gm * 1024 + k0 + kq]
                                   : make_float4(0.f, 0.f, 0.f, 0.f);
            As[kq + 0][m] = v.x; As[kq + 1][m] = v.y; As[kq + 2][m] = v.z; As[kq + 3][m] = v.w;
            int gn = n0 + m;
            float4 w = (gn < 5000) ? *(const float4*)&wo[(size_t)gn * 1024 + k0 + kq]
                                   : make_float4(0.f, 0.f, 0.f, 0.f);
            Bs[kq + 0][m] = w.x; Bs[kq + 1][m] = w.y; Bs[kq + 2][m] = w.z; Bs[kq + 3][m] = w.w;
        }
        __syncthreads();
        #pragma unroll 16
        for (int kk = 0; kk < 64; ++kk) {
            float4 av = *(const float4*)&As[kk][tr << 2];
            float4 bv = *(const float4*)&Bs[kk][tc << 2];
            float a[4] = {av.x, av.y, av.z, av.w};
            float b[4] = {bv.x, bv.y, bv.z, bv.w};
            #pragma unroll
            for (int i = 0; i < 4; i++)
                #pragma unroll
                for (int j = 0; j < 4; j++) acc[i][j] += a[i] * b[j];
        }
        __syncthreads();
    }
    #pragma unroll
    for (int i = 0; i < 4; i++) {
        int m = m0 + (tr << 2) + i;
        if (m >= 3232) continue;
        int b = m & 31, o = m >> 5;
        #pragma unroll
        for (int j = 0; j < 4; j++) {
            int v = n0 + (tc << 2) + j;
            if (v < 5000)
                out[((size_t)b * 101 + o) * 5000 + v] = acc[i][j] + bo[v];
        }
    }
}

extern "C" void kernel_launch(void* const* d_in, const int* in_sizes, int n_in,
                              void* d_out, int out_size, void* d_ws, size_t ws_size,
                              hipStream_t stream) {
    const float* hpad   = (const float*)d_in[0];
    const int*   ys     = (const int*)d_in[1];
    const float* w_enc  = (const float*)d_in[2];
    const float* b_enc  = (const float*)d_in[3];
    const float* w_dec  = (const float*)d_in[4];
    const float* w_att  = (const float*)d_in[5];
    const float* w_conv = (const float*)d_in[6];
    const float* w_gvec = (const float*)d_in[7];
    const float* b_gvec = (const float*)d_in[8];
    const float* embed  = (const float*)d_in[9];
    const float* w_ih   = (const float*)d_in[10];
    const float* w_hh   = (const float*)d_in[11];
    const float* b_ih   = (const float*)d_in[12];
    const float* b_hh   = (const float*)d_in[13];
    const float* w_out  = (const float*)d_in[14];
    const float* b_out  = (const float*)d_in[15];
    float* ws  = (float*)d_ws;
    float* out = (float*)d_out;

    k_init<<<128, 256, 0, stream>>>(ws);
    k_pre<<<dim3(8, 500), 256, 0, stream>>>(hpad, w_enc, b_enc, ws + OFF_PRE);

    for (int step = 0; step < OLEN_; ++step) {
        k_prepA<<<1600, 256, 0, stream>>>(w_dec, w_conv, w_ih, w_hh, embed, ys, ws, step);
        k_energy2<<<800, 256, 0, stream>>>(w_att, w_gvec, b_gvec, ws);
        k_ctx2<<<1024, 128, 0, stream>>>(hpad, ws);
        k_gl<<<128, 128, 0, stream>>>(w_ih, b_ih, b_hh, ws, step);
    }

    k_out<<<dim3(79, 51), 256, 0, stream>>>(ws + OFF_ZALL, w_out, b_out, out);
}